// Round 3
// baseline (1886.338 us; speedup 1.0000x reference)
//
#include <hip/hip_runtime.h>
#include <math.h>

// Problem constants
constexpr int NB = 32, NL = 32, ND = 512, NHID = 512, NSTEPS = 31;
constexpr int KC = 1024;    // 2H
constexpr int NC5 = 2560;   // 5H
constexpr int BH = NB * NHID;          // 16384
constexpr int STATE_F = NL * BH;       // 524288 floats (c state)
constexpr int STATE_H = NL * NB * NHID;// 524288 halves per split plane
constexpr int NROWS = NSTEPS * NB;     // 992 (j,b) rows
constexpr int NHT = 16;                // h-tiles of 32 cols

// Workspace layout (float offsets). ~23 MB total.
constexpr size_t OFF_C0  = 0;
constexpr size_t OFF_C1  = OFF_C0 + STATE_F;
constexpr size_t OFF_NH  = OFF_C1 + STATE_F;
constexpr size_t OFF_NC  = OFF_NH + STATE_F;
constexpr size_t OFF_PT  = OFF_NC + STATE_F;          // partials [16][992]
constexpr size_t OFF_ML  = OFF_PT + 16384;
constexpr size_t OFF_HI0 = OFF_ML + 64;               // half planes (f32 units)
constexpr size_t OFF_HI1 = OFF_HI0 + STATE_H / 2;
constexpr size_t OFF_LO0 = OFF_HI1 + STATE_H / 2;
constexpr size_t OFF_LO1 = OFF_LO0 + STATE_H / 2;
constexpr size_t OFF_WTH = OFF_LO1 + STATE_H / 2;     // W^T hi [n][k] halves
constexpr size_t OFF_WTL = OFF_WTH + (size_t)NC5 * KC / 2;

typedef _Float16 half8  __attribute__((ext_vector_type(8)));
typedef _Float16 half4  __attribute__((ext_vector_type(4)));
typedef float    f32x4  __attribute__((ext_vector_type(4)));
typedef float    f32x16 __attribute__((ext_vector_type(16)));

constexpr float INV2048 = 1.f / 2048.f;

__device__ __forceinline__ float sigf(float x) { return 1.f / (1.f + expf(-x)); }

__global__ void prep_kernel(const int* __restrict__ len, int* __restrict__ maxlen) {
    if (threadIdx.x == 0) {
        int m = 2;
        for (int b = 0; b < NB; ++b) m = max(m, len[b]);
        *maxlen = m;
    }
}

// W_comp (1024 x 2560 f32) -> transposed split planes Wth/Wtl [n][k] fp16.
__global__ __launch_bounds__(256) void wsplit_kernel(
    const float* __restrict__ W, _Float16* __restrict__ Wth, _Float16* __restrict__ Wtl)
{
    __shared__ float t[32][33];
    const int n0 = blockIdx.x * 32, k0 = blockIdx.y * 32;
    const int tid = threadIdx.x;
    const int c = tid & 31, r8 = tid >> 5;
#pragma unroll
    for (int p = 0; p < 4; ++p) {
        int r = p * 8 + r8;
        t[r][c] = W[(size_t)(k0 + r) * NC5 + n0 + c];
    }
    __syncthreads();
    const int nl = tid >> 3, k4 = (tid & 7) * 4;
    half4 vh, vl;
#pragma unroll
    for (int i = 0; i < 4; ++i) {
        float v = t[k4 + i][nl];
        _Float16 hh = (_Float16)v;
        vh[i] = hh;
        vl[i] = (_Float16)((v - (float)hh) * 2048.f);
    }
    size_t o = (size_t)(n0 + nl) * KC + k0 + k4;
    *(half4*)&Wth[o] = vh;
    *(half4*)&Wtl[o] = vl;
}

// hc = inp @ W_word + b_word. n<512 -> h split planes + leaf nodes; else c f32.
__global__ __launch_bounds__(256) void word_gemm64(
    const float* __restrict__ A, const float* __restrict__ W,
    const float* __restrict__ bias,
    _Float16* __restrict__ hi0, _Float16* __restrict__ lo0,
    float* __restrict__ cst, float* __restrict__ out)
{
    const int m0 = blockIdx.x * 64;
    const int n0 = blockIdx.y * 64;
    const int tid = threadIdx.x;
    const int tx = tid & 15, ty = tid >> 4;
    __shared__ float As[16][64];
    __shared__ float Bs[16][64];
    float acc[4][4];
#pragma unroll
    for (int i = 0; i < 4; ++i)
#pragma unroll
        for (int j = 0; j < 4; ++j) acc[i][j] = 0.f;

    for (int kt = 0; kt < ND; kt += 16) {
        {
            int row = tid >> 2, kq = tid & 3;
            float4 v = *(const float4*)(A + (size_t)(m0 + row) * ND + kt + kq * 4);
            As[kq * 4 + 0][row] = v.x;
            As[kq * 4 + 1][row] = v.y;
            As[kq * 4 + 2][row] = v.z;
            As[kq * 4 + 3][row] = v.w;
            int kr = tid >> 4, nq = tid & 15;
            float4 vb = *(const float4*)(W + (size_t)(kt + kr) * 1024 + n0 + nq * 4);
            *(float4*)&Bs[kr][nq * 4] = vb;
        }
        __syncthreads();
#pragma unroll
        for (int kk = 0; kk < 16; ++kk) {
            float a0 = As[kk][ty * 4 + 0], a1 = As[kk][ty * 4 + 1];
            float a2 = As[kk][ty * 4 + 2], a3 = As[kk][ty * 4 + 3];
            float4 bv = *(float4*)&Bs[kk][tx * 4];
            acc[0][0] = fmaf(a0, bv.x, acc[0][0]); acc[0][1] = fmaf(a0, bv.y, acc[0][1]);
            acc[0][2] = fmaf(a0, bv.z, acc[0][2]); acc[0][3] = fmaf(a0, bv.w, acc[0][3]);
            acc[1][0] = fmaf(a1, bv.x, acc[1][0]); acc[1][1] = fmaf(a1, bv.y, acc[1][1]);
            acc[1][2] = fmaf(a1, bv.z, acc[1][2]); acc[1][3] = fmaf(a1, bv.w, acc[1][3]);
            acc[2][0] = fmaf(a2, bv.x, acc[2][0]); acc[2][1] = fmaf(a2, bv.y, acc[2][1]);
            acc[2][2] = fmaf(a2, bv.z, acc[2][2]); acc[2][3] = fmaf(a2, bv.w, acc[2][3]);
            acc[3][0] = fmaf(a3, bv.x, acc[3][0]); acc[3][1] = fmaf(a3, bv.y, acc[3][1]);
            acc[3][2] = fmaf(a3, bv.z, acc[3][2]); acc[3][3] = fmaf(a3, bv.w, acc[3][3]);
        }
        __syncthreads();
    }
    float* nodes = out + 2 * BH;
#pragma unroll
    for (int i = 0; i < 4; ++i) {
        int r = m0 + ty * 4 + i;
        int b = r >> 5, l = r & 31;
#pragma unroll
        for (int jn = 0; jn < 4; ++jn) {
            int n = n0 + tx * 4 + jn;
            float v = acc[i][jn] + bias[n];
            if (n < NHID) {
                size_t si = ((size_t)l * NB + b) * NHID + n;
                _Float16 hh = (_Float16)v;
                hi0[si] = hh;
                lo0[si] = (_Float16)((v - (float)hh) * 2048.f);
                nodes[((size_t)b * 63 + l) * NHID + n] = v;
            } else {
                cst[((size_t)l * NB + b) * NHID + (n - NHID)] = v;
            }
        }
    }
}

// Fused cell GEMM + activations + logit partials.
// Block = (ht, jt): rows m = jt*64 + mg*32 + b (j = jt*2+mg), cols = 5 gates x 32 h.
// 4 waves = 2 m-groups x 2 k-halves; 32x32x16 f16 MFMA, split-fp16 3-product.
// A and B fragments loaded DIRECTLY from global (16B/lane contiguous) - no LDS
// in the K-loop. LDS used once for cross-k-wave reduction + epilogue exchange.
__global__ __launch_bounds__(256, 2) void cell_fused(
    const _Float16* __restrict__ hi, const _Float16* __restrict__ lo,
    const _Float16* __restrict__ Wth, const _Float16* __restrict__ Wtl,
    const float* __restrict__ bias, const float* __restrict__ q,
    const float* __restrict__ cst,
    float* __restrict__ nh, float* __restrict__ nc,
    float* __restrict__ partials,
    const int* __restrict__ maxlen_p, int step)
{
    int actmax = *maxlen_p - 1 - step;
    if (actmax < 1) actmax = 1;
    const int ht = blockIdx.x, jt = blockIdx.y;
    if (jt * 2 >= actmax) return;

    const int tid = threadIdx.x;
    const int wave = tid >> 6, lane = tid & 63;
    const int mg = wave & 1, kw = wave >> 1;
    const int l5 = lane >> 5, ln = lane & 31;

    const int j  = jt * 2 + mg;              // 0..31 (j==31 rows are discarded)
    const int jA = min(j + kw, 31);          // state row feeding this k-half
    const int h0 = ht * 32;

    const _Float16* aHi = hi + ((size_t)jA * NB + ln) * NHID;
    const _Float16* aLo = lo + ((size_t)jA * NB + ln) * NHID;
    const _Float16* pBh[5];
    const _Float16* pBl[5];
#pragma unroll
    for (int g = 0; g < 5; ++g) {
        size_t o = (size_t)(g * 512 + h0 + ln) * KC + kw * 512;
        pBh[g] = Wth + o;
        pBl[g] = Wtl + o;
    }

    f32x16 acc1[5], acc2[5];
#pragma unroll
    for (int g = 0; g < 5; ++g) { acc1[g] = (f32x16)0.f; acc2[g] = (f32x16)0.f; }

    for (int ks = 0; ks < 32; ++ks) {
        const int ko = ks * 16 + l5 * 8;     // k offset within the 512 half
        half8 Ah = *(const half8*)(aHi + ko);
        half8 Al = *(const half8*)(aLo + ko);
#pragma unroll
        for (int g = 0; g < 5; ++g) {
            half8 Bh = *(const half8*)(pBh[g] + ko);
            half8 Bl = *(const half8*)(pBl[g] + ko);
            acc1[g] = __builtin_amdgcn_mfma_f32_32x32x16_f16(Ah, Bh, acc1[g], 0, 0, 0);
            acc2[g] = __builtin_amdgcn_mfma_f32_32x32x16_f16(Ah, Bl, acc2[g], 0, 0, 0);
            acc2[g] = __builtin_amdgcn_mfma_f32_32x32x16_f16(Al, Bh, acc2[g], 0, 0, 0);
        }
        if ((ks & 7) == 7) __syncthreads();  // align the two m-groups' k-windows (L1 reuse)
    }

    // Cross-k-wave reduction through LDS. C/D: col=lane&31, row=(a&3)+8*(a>>2)+4*l5.
    __shared__ float ldsC[2][5][32][32];
    if (kw == 1) {
#pragma unroll
        for (int g = 0; g < 5; ++g)
#pragma unroll
            for (int a = 0; a < 16; ++a) {
                int row = (a & 3) + 8 * (a >> 2) + 4 * l5;
                ldsC[mg][g][row][ln] = acc1[g][a] + acc2[g][a] * INV2048;
            }
    }
    __syncthreads();
    if (kw == 0) {
#pragma unroll
        for (int g = 0; g < 5; ++g)
#pragma unroll
            for (int a = 0; a < 16; ++a) {
                int row = (a & 3) + 8 * (a >> 2) + 4 * l5;
                float v = acc1[g][a] + acc2[g][a] * INV2048 + ldsC[mg][g][row][ln];
                ldsC[mg][g][row][ln] = v;
            }
    }
    __syncthreads();

    // Epilogue: activations + nh/nc + per-row logit partials. 512 float4 cells.
#pragma unroll
    for (int it = 0; it < 2; ++it) {
        int fidx = tid + it * 256;           // 0..511
        int row = fidx >> 3;                 // 0..63
        int hq = fidx & 7;
        int mgr = row >> 5, r32 = row & 31;
        int jj = jt * 2 + mgr;
        int bb = r32;
        int hbase = h0 + hq * 4;

        float gv[5][4];
#pragma unroll
        for (int g = 0; g < 5; ++g) {
            float4 t = *(float4*)&ldsC[mgr][g][r32][hq * 4];
            float4 bi = *(const float4*)&bias[g * 512 + hbase];
            gv[g][0] = t.x + bi.x; gv[g][1] = t.y + bi.y;
            gv[g][2] = t.z + bi.z; gv[g][3] = t.w + bi.w;
        }
        int jr = min(jj, 30);
        float4 cl4 = *(const float4*)&cst[((size_t)jr * NB + bb) * NHID + hbase];
        float4 cr4 = *(const float4*)&cst[((size_t)(jr + 1) * NB + bb) * NHID + hbase];
        float clv[4] = {cl4.x, cl4.y, cl4.z, cl4.w};
        float crv[4] = {cr4.x, cr4.y, cr4.z, cr4.w};
        float4 q4 = *(const float4*)&q[hbase];
        float qv[4] = {q4.x, q4.y, q4.z, q4.w};

        float nhv[4], ncv[4], lsum = 0.f;
#pragma unroll
        for (int i = 0; i < 4; ++i) {
            float ig = gv[0][i], fl = gv[1][i], fr = gv[2][i], u = gv[3][i], o = gv[4][i];
            float c = clv[i] * sigf(fl + 1.f) + crv[i] * sigf(fr + 1.f)
                    + tanhf(u) * sigf(ig);
            float h = sigf(o) * tanhf(c);
            ncv[i] = c; nhv[i] = h;
            lsum = fmaf(h, qv[i], lsum);
        }
        bool valid = (jj < actmax) && (jj == jr);
        if (valid) {
            size_t o = ((size_t)jj * NB + bb) * NHID + hbase;
            *(float4*)&nh[o] = make_float4(nhv[0], nhv[1], nhv[2], nhv[3]);
            *(float4*)&nc[o] = make_float4(ncv[0], ncv[1], ncv[2], ncv[3]);
        }
        // deterministic per-row sum over the 8 hq threads (consecutive lanes)
        lsum += __shfl_xor(lsum, 1);
        lsum += __shfl_xor(lsum, 2);
        lsum += __shfl_xor(lsum, 4);
        if (valid && hq == 0)
            partials[(size_t)ht * NROWS + jj * NB + bb] = lsum;
    }
}

// Per-(b, j) block: argmax over summed partials, ping-pong state merge/copy,
// node + final hf/cf writes (block j==0).
__global__ __launch_bounds__(256) void update_kernel(
    const float* __restrict__ partials, const int* __restrict__ len,
    const float* __restrict__ nh, const float* __restrict__ nc,
    const _Float16* __restrict__ hiC, const _Float16* __restrict__ loC,
    const float* __restrict__ cC,
    _Float16* __restrict__ hiN, _Float16* __restrict__ loN,
    float* __restrict__ cN,
    float* __restrict__ out, int step)
{
    const int b = blockIdx.x;
    const int j = blockIdx.y;
    const int tid = threadIdx.x;
    __shared__ int sk, smerge;
    if (tid < 64) {
        int actb = len[b] - 1 - step;
        float v = -1e30f;
        int idx = tid;
        if (tid < NSTEPS && tid < actb) {
            float s0 = 0.f, s1 = 0.f, s2 = 0.f, s3 = 0.f;
#pragma unroll
            for (int y = 0; y < NHT; y += 4) {
                s0 += partials[(size_t)(y + 0) * NROWS + tid * NB + b];
                s1 += partials[(size_t)(y + 1) * NROWS + tid * NB + b];
                s2 += partials[(size_t)(y + 2) * NROWS + tid * NB + b];
                s3 += partials[(size_t)(y + 3) * NROWS + tid * NB + b];
            }
            v = (s0 + s1) + (s2 + s3);
        }
#pragma unroll
        for (int off = 32; off > 0; off >>= 1) {
            float ov = __shfl_down(v, off);
            int   oi = __shfl_down(idx, off);
            if (ov > v || (ov == v && oi < idx)) { v = ov; idx = oi; }
        }
        if (tid == 0) { sk = idx; smerge = ((len[b] - 1 - step) >= 1) ? 1 : 0; }
    }
    __syncthreads();
    const int k = sk, merge = smerge;
    const int last = (step == NSTEPS - 1);

    int srcj = j, useNew = 0, zero = 0;
    if (merge) {
        if (j == k) useNew = 1;
        else if (j > k) { srcj = j + 1; if (srcj > NL - 1) zero = 1; }
    }
    for (int h = tid; h < NHID; h += 256) {
        _Float16 hh, hl; float cv;
        if (zero) { hh = (_Float16)0.f; hl = (_Float16)0.f; cv = 0.f; }
        else if (useNew) {
            float x = nh[((size_t)k * NB + b) * NHID + h];
            hh = (_Float16)x;
            hl = (_Float16)((x - (float)hh) * 2048.f);
            cv = nc[((size_t)k * NB + b) * NHID + h];
        } else {
            size_t si = ((size_t)srcj * NB + b) * NHID + h;
            hh = hiC[si]; hl = loC[si]; cv = cC[si];
        }
        size_t di = ((size_t)j * NB + b) * NHID + h;
        hiN[di] = hh; loN[di] = hl; cN[di] = cv;
    }

    if (j == 0) {
        float* hf = out;
        float* cf = out + BH;
        float* noderow = out + 2 * BH + ((size_t)b * 63 + 32 + step) * NHID;
        for (int h = tid; h < NHID; h += 256) {
            float nodev;
            if (!last) {
                nodev = merge ? nh[((size_t)k * NB + b) * NHID + h]
                              : nh[(size_t)b * NHID + h];
            } else {
                if (merge) {
                    nodev = nh[(size_t)b * NHID + h];
                    hf[b * NHID + h] = nodev;
                    cf[b * NHID + h] = nc[(size_t)b * NHID + h];
                } else {
                    size_t si = (size_t)b * NHID + h;
                    nodev = (float)hiC[si] + (float)loC[si] * INV2048;
                    hf[b * NHID + h] = nodev;
                    cf[b * NHID + h] = cC[si];
                }
            }
            noderow[h] = nodev;
        }
    }
}

extern "C" void kernel_launch(void* const* d_in, const int* in_sizes, int n_in,
                              void* d_out, int out_size, void* d_ws, size_t ws_size,
                              hipStream_t stream) {
    const float* inp    = (const float*)d_in[0];
    const int*   length = (const int*)d_in[1];
    const float* W_word = (const float*)d_in[2];
    const float* b_word = (const float*)d_in[3];
    const float* W_comp = (const float*)d_in[4];
    const float* b_comp = (const float*)d_in[5];
    const float* q      = (const float*)d_in[6];
    float* out = (float*)d_out;
    float* ws  = (float*)d_ws;

    float*     cbuf[2] = { ws + OFF_C0, ws + OFF_C1 };
    _Float16*  hbuf[2] = { (_Float16*)(ws + OFF_HI0), (_Float16*)(ws + OFF_HI1) };
    _Float16*  lbuf[2] = { (_Float16*)(ws + OFF_LO0), (_Float16*)(ws + OFF_LO1) };
    float*     nh      = ws + OFF_NH;
    float*     nc      = ws + OFF_NC;
    float*     part    = ws + OFF_PT;
    int*       maxlen  = (int*)(ws + OFF_ML);
    _Float16*  Wth     = (_Float16*)(ws + OFF_WTH);
    _Float16*  Wtl     = (_Float16*)(ws + OFF_WTL);

    prep_kernel<<<1, 64, 0, stream>>>(length, maxlen);
    wsplit_kernel<<<dim3(NC5 / 32, KC / 32), 256, 0, stream>>>(W_comp, Wth, Wtl);
    word_gemm64<<<dim3(16, 16), 256, 0, stream>>>(inp, W_word, b_word,
                                                  hbuf[0], lbuf[0], cbuf[0], out);
    for (int i = 0; i < NSTEPS; ++i) {
        int cur = i & 1, nxt = cur ^ 1;
        cell_fused<<<dim3(NHT, 16), 256, 0, stream>>>(hbuf[cur], lbuf[cur],
                                                      Wth, Wtl, b_comp, q,
                                                      cbuf[cur], nh, nc, part,
                                                      maxlen, i);
        update_kernel<<<dim3(NB, NL), 256, 0, stream>>>(part, length, nh, nc,
                                                        hbuf[cur], lbuf[cur], cbuf[cur],
                                                        hbuf[nxt], lbuf[nxt], cbuf[nxt],
                                                        out, i);
    }
}

// Round 4
// 793.348 us; speedup vs baseline: 2.3777x; 2.3777x over previous
//
#include <hip/hip_runtime.h>
#include <math.h>

// Problem constants
constexpr int NB = 32, NL = 32, ND = 512, NHID = 512, NSTEPS = 31;
constexpr int NC5 = 2560;          // 5H
constexpr int BH = NB * NHID;      // 16384
constexpr int HSLOT_Z = 32;        // zero state slot id (33 slots total)

constexpr float INV2048 = 1.f / 2048.f;

typedef _Float16 half8  __attribute__((ext_vector_type(8)));
typedef _Float16 half4  __attribute__((ext_vector_type(4)));
typedef float    f32x16 __attribute__((ext_vector_type(16)));

// ---------------- workspace layout (float offsets) ----------------
constexpr size_t OFF_GRAW = 0;                        // [31][32][2560] f32
constexpr size_t OFF_PNH  = OFF_GRAW + (size_t)31 * 32 * 2560;   // [31][32][512]
constexpr size_t OFF_PNC  = OFF_PNH + (size_t)31 * 32 * 512;
constexpr size_t OFF_PLOG = OFF_PNC + (size_t)31 * 32 * 512;     // [31][32]
constexpr size_t OFF_CST  = OFF_PLOG + 1024;          // [33][32][512] f32
constexpr size_t OFF_HHI  = OFF_CST + (size_t)33 * 32 * 512;     // halves [33][32][512]
constexpr size_t OFF_HLO  = OFF_HHI + (size_t)33 * 32 * 512 / 2;
constexpr size_t OFF_WTH  = OFF_HLO + (size_t)33 * 32 * 512 / 2; // W^T hi [n][k] halves
constexpr size_t OFF_WTL  = OFF_WTH + (size_t)NC5 * 1024 / 2;
constexpr size_t OFF_INT  = OFF_WTL + (size_t)NC5 * 1024 / 2;    // int region
constexpr size_t OFF_LIST = OFF_INT + 4096;           // 2 lists x 1024 x int4

__device__ __forceinline__ float sigf(float x) { return 1.f / (1.f + expf(-x)); }

// ---------------- init: indices, zero slot, step-0 list ----------------
__global__ __launch_bounds__(256) void init_kernel(
    int* __restrict__ pidx, int* __restrict__ hidx, int* __restrict__ prevk,
    int* __restrict__ cnt, int4* __restrict__ list0,
    _Float16* __restrict__ hHi, _Float16* __restrict__ hLo, float* __restrict__ cSt)
{
    const int blk = blockIdx.x, tid = threadIdx.x;
    if (blk < 32) {
        if (tid < 32) { pidx[blk * 32 + tid] = min(tid, 30); hidx[blk * 32 + tid] = tid; }
        if (tid == 0) prevk[blk] = -1;
        if (tid < 31) list0[tid * 32 + blk] = make_int4(blk, tid, tid, tid + 1);
    } else if (blk == 32) {
        const size_t zb = (size_t)HSLOT_Z * NB * NHID;
        for (int i = tid; i < NB * NHID; i += 256) {
            hHi[zb + i] = (_Float16)0.f;
            hLo[zb + i] = (_Float16)0.f;
            cSt[zb + i] = 0.f;
        }
    } else {
        if (tid == 0) { cnt[0] = 992; cnt[1] = 0; }
    }
}

// ---------------- W_comp -> transposed split fp16 planes ----------------
__global__ __launch_bounds__(256) void wsplit_kernel(
    const float* __restrict__ W, _Float16* __restrict__ Wth, _Float16* __restrict__ Wtl)
{
    __shared__ float t[32][33];
    const int n0 = blockIdx.x * 32, k0 = blockIdx.y * 32;
    const int tid = threadIdx.x;
    const int c = tid & 31, r8 = tid >> 5;
#pragma unroll
    for (int p = 0; p < 4; ++p) {
        int r = p * 8 + r8;
        t[r][c] = W[(size_t)(k0 + r) * NC5 + n0 + c];
    }
    __syncthreads();
    const int nl = tid >> 3, k4 = (tid & 7) * 4;
    half4 vh, vl;
#pragma unroll
    for (int i = 0; i < 4; ++i) {
        float v = t[k4 + i][nl];
        _Float16 hh = (_Float16)v;
        vh[i] = hh;
        vl[i] = (_Float16)((v - (float)hh) * 2048.f);
    }
    size_t o = (size_t)(n0 + nl) * 1024 + k0 + k4;
    *(half4*)&Wth[o] = vh;
    *(half4*)&Wtl[o] = vl;
}

// ---------------- word GEMM: leaves -> state slots 0..31 ----------------
__global__ __launch_bounds__(256) void word_gemm64(
    const float* __restrict__ A, const float* __restrict__ W,
    const float* __restrict__ bias,
    _Float16* __restrict__ hi0, _Float16* __restrict__ lo0,
    float* __restrict__ cst, float* __restrict__ out)
{
    const int m0 = blockIdx.x * 64;
    const int n0 = blockIdx.y * 64;
    const int tid = threadIdx.x;
    const int tx = tid & 15, ty = tid >> 4;
    __shared__ float As[16][64];
    __shared__ float Bs[16][64];
    float acc[4][4];
#pragma unroll
    for (int i = 0; i < 4; ++i)
#pragma unroll
        for (int j = 0; j < 4; ++j) acc[i][j] = 0.f;

    for (int kt = 0; kt < ND; kt += 16) {
        {
            int row = tid >> 2, kq = tid & 3;
            float4 v = *(const float4*)(A + (size_t)(m0 + row) * ND + kt + kq * 4);
            As[kq * 4 + 0][row] = v.x;
            As[kq * 4 + 1][row] = v.y;
            As[kq * 4 + 2][row] = v.z;
            As[kq * 4 + 3][row] = v.w;
            int kr = tid >> 4, nq = tid & 15;
            float4 vb = *(const float4*)(W + (size_t)(kt + kr) * 1024 + n0 + nq * 4);
            *(float4*)&Bs[kr][nq * 4] = vb;
        }
        __syncthreads();
#pragma unroll
        for (int kk = 0; kk < 16; ++kk) {
            float a0 = As[kk][ty * 4 + 0], a1 = As[kk][ty * 4 + 1];
            float a2 = As[kk][ty * 4 + 2], a3 = As[kk][ty * 4 + 3];
            float4 bv = *(float4*)&Bs[kk][tx * 4];
            acc[0][0] = fmaf(a0, bv.x, acc[0][0]); acc[0][1] = fmaf(a0, bv.y, acc[0][1]);
            acc[0][2] = fmaf(a0, bv.z, acc[0][2]); acc[0][3] = fmaf(a0, bv.w, acc[0][3]);
            acc[1][0] = fmaf(a1, bv.x, acc[1][0]); acc[1][1] = fmaf(a1, bv.y, acc[1][1]);
            acc[1][2] = fmaf(a1, bv.z, acc[1][2]); acc[1][3] = fmaf(a1, bv.w, acc[1][3]);
            acc[2][0] = fmaf(a2, bv.x, acc[2][0]); acc[2][1] = fmaf(a2, bv.y, acc[2][1]);
            acc[2][2] = fmaf(a2, bv.z, acc[2][2]); acc[2][3] = fmaf(a2, bv.w, acc[2][3]);
            acc[3][0] = fmaf(a3, bv.x, acc[3][0]); acc[3][1] = fmaf(a3, bv.y, acc[3][1]);
            acc[3][2] = fmaf(a3, bv.z, acc[3][2]); acc[3][3] = fmaf(a3, bv.w, acc[3][3]);
        }
        __syncthreads();
    }
    float* nodes = out + 2 * BH;
#pragma unroll
    for (int i = 0; i < 4; ++i) {
        int r = m0 + ty * 4 + i;
        int b = r >> 5, l = r & 31;
#pragma unroll
        for (int jn = 0; jn < 4; ++jn) {
            int n = n0 + tx * 4 + jn;
            float v = acc[i][jn] + bias[n];
            if (n < NHID) {
                size_t si = ((size_t)l * NB + b) * NHID + n;
                _Float16 hh = (_Float16)v;
                hi0[si] = hh;
                lo0[si] = (_Float16)((v - (float)hh) * 2048.f);
                nodes[((size_t)b * 63 + l) * NHID + n] = v;
            } else {
                cst[((size_t)l * NB + b) * NHID + (n - NHID)] = v;
            }
        }
    }
}

// ---------------- list-driven pair GEMM (raw gates, no bias) ----------------
// Block: 32 list rows (blockIdx.y) x 32 cols (blockIdx.x of 80). 4 waves split
// K=1024 into 256-chunks aligned to the left/right 512 boundary. Split-fp16
// 3-product 32x32x16 MFMA; operands loaded straight from global (L2-hot W^T).
__global__ __launch_bounds__(256) void pair_gemm(
    const _Float16* __restrict__ hHi, const _Float16* __restrict__ hLo,
    const _Float16* __restrict__ Wth, const _Float16* __restrict__ Wtl,
    const int4* __restrict__ list, const int* __restrict__ cnt_cur,
    int* __restrict__ cnt_next, float* __restrict__ graw)
{
    if (blockIdx.x == 0 && blockIdx.y == 0 && threadIdx.x == 0) *cnt_next = 0;
    const int count = *cnt_cur;
    const int mt = blockIdx.y;
    if (mt * 32 >= count) return;
    const int nt = blockIdx.x;             // 0..79 -> cols nt*32..nt*32+31
    const int tid = threadIdx.x;
    const int kw = tid >> 6;               // wave 0..3 = K chunk
    const int lane = tid & 63;
    const int l5 = lane >> 5, ln = lane & 31;

    const int r = mt * 32 + ln;
    const int rc = min(r, count - 1);
    const int4 d = list[rc];               // {b, slot, left, right}
    const int hs = (kw < 2) ? d.z : d.w;
    const int koff = (kw & 1) * 256 + l5 * 8;

    const _Float16* aHiP = hHi + ((size_t)hs * NB + d.x) * NHID + koff;
    const _Float16* aLoP = hLo + ((size_t)hs * NB + d.x) * NHID + koff;
    const _Float16* bHiP = Wth + (size_t)(nt * 32 + ln) * 1024 + kw * 256 + l5 * 8;
    const _Float16* bLoP = Wtl + (size_t)(nt * 32 + ln) * 1024 + kw * 256 + l5 * 8;

    f32x16 acc1 = (f32x16)0.f, acc2 = (f32x16)0.f;
#pragma unroll
    for (int ks = 0; ks < 16; ++ks) {
        const int ko = ks * 16;
        half8 Ah = *(const half8*)(aHiP + ko);
        half8 Al = *(const half8*)(aLoP + ko);
        half8 Bh = *(const half8*)(bHiP + ko);
        half8 Bl = *(const half8*)(bLoP + ko);
        acc1 = __builtin_amdgcn_mfma_f32_32x32x16_f16(Ah, Bh, acc1, 0, 0, 0);
        acc2 = __builtin_amdgcn_mfma_f32_32x32x16_f16(Ah, Bl, acc2, 0, 0, 0);
        acc2 = __builtin_amdgcn_mfma_f32_32x32x16_f16(Al, Bh, acc2, 0, 0, 0);
    }

    // cross-wave reduce. C/D: col=lane&31, row=(a&3)+8*(a>>2)+4*(lane>>5).
    __shared__ float red[4][32][32];
#pragma unroll
    for (int a = 0; a < 16; ++a) {
        int row = (a & 3) + 8 * (a >> 2) + 4 * l5;
        red[kw][row][ln] = acc1[a] + acc2[a] * INV2048;
    }
    __syncthreads();
    {
        const int row = tid >> 3, c0 = (tid & 7) * 4;
        if (mt * 32 + row < count) {
            const int4 dr = list[mt * 32 + row];
            float4 s;
            s.x = (red[0][row][c0+0] + red[1][row][c0+0]) + (red[2][row][c0+0] + red[3][row][c0+0]);
            s.y = (red[0][row][c0+1] + red[1][row][c0+1]) + (red[2][row][c0+1] + red[3][row][c0+1]);
            s.z = (red[0][row][c0+2] + red[1][row][c0+2]) + (red[2][row][c0+2] + red[3][row][c0+2]);
            s.w = (red[0][row][c0+3] + red[1][row][c0+3]) + (red[2][row][c0+3] + red[3][row][c0+3]);
            *(float4*)&graw[((size_t)dr.y * NB + dr.x) * NC5 + nt * 32 + c0] = s;
        }
    }
}

// ---------------- per-batch update: activate fresh, argmax, merge ----------------
__global__ __launch_bounds__(256) void update_kernel(
    const float* __restrict__ graw, const float* __restrict__ bias,
    const float* __restrict__ q, const int* __restrict__ len,
    float* __restrict__ pnh, float* __restrict__ pnc, float* __restrict__ plog,
    _Float16* __restrict__ hHi, _Float16* __restrict__ hLo, float* __restrict__ cSt,
    int* __restrict__ pidx, int* __restrict__ hidx, int* __restrict__ prevk,
    int4* __restrict__ nextlist, int* __restrict__ cnt_next,
    float* __restrict__ out, int step)
{
    const int b = blockIdx.x;
    const int tid = threadIdx.x;
    __shared__ int s_pidx[32], s_hidx[32];
    if (tid < 32) { s_pidx[tid] = pidx[b * 32 + tid]; s_hidx[tid] = hidx[b * 32 + tid]; }
    const int pk = prevk[b];
    __syncthreads();

    // Phase A: activate fresh pairs (step 0: all 31; else <=2 from prevk)
    int nf;
    if (step == 0) nf = 31; else if (pk < 0) nf = 0; else nf = (pk >= 1) ? 2 : 1;
    __shared__ float lred[4];
    for (int f = 0; f < nf; ++f) {
        const int j = (step == 0) ? f : (pk - (nf - 1) + f);
        const int slot = s_pidx[j];
        const int ls = s_hidx[j];
        const int rs = s_hidx[j + 1];      // j <= 30 always
        const float* gr = graw + ((size_t)slot * NB + b) * NC5;
        const float* clp = cSt + ((size_t)ls * NB + b) * NHID;
        const float* crp = cSt + ((size_t)rs * NB + b) * NHID;
        float lpart = 0.f;
        for (int h = tid; h < NHID; h += 256) {
            float ig = gr[h]          + bias[h];
            float fl = gr[512 + h]    + bias[512 + h];
            float fr = gr[1024 + h]   + bias[1024 + h];
            float u  = gr[1536 + h]   + bias[1536 + h];
            float o  = gr[2048 + h]   + bias[2048 + h];
            float cl = clp[h], cr = crp[h];
            float c  = cl * sigf(fl + 1.f) + cr * sigf(fr + 1.f) + tanhf(u) * sigf(ig);
            float hh = sigf(o) * tanhf(c);
            size_t po = ((size_t)slot * NB + b) * NHID + h;
            pnh[po] = hh;
            pnc[po] = c;
            lpart = fmaf(hh, q[h], lpart);
        }
#pragma unroll
        for (int off = 32; off > 0; off >>= 1) lpart += __shfl_down(lpart, off);
        if ((tid & 63) == 0) lred[tid >> 6] = lpart;
        __syncthreads();
        if (tid == 0) plog[(size_t)slot * NB + b] = (lred[0] + lred[1]) + (lred[2] + lred[3]);
        __syncthreads();
    }

    // Phase B: argmax over j < actb (first-index tie-break)
    const int actb = len[b] - 1 - step;
    const int merge = actb >= 1;
    __shared__ int sk;
    if (tid < 64) {
        float v = -1e30f;
        int idx = tid;
        if (tid < actb && tid < 31) v = plog[(size_t)s_pidx[tid] * NB + b];
#pragma unroll
        for (int off = 32; off > 0; off >>= 1) {
            float ov = __shfl_down(v, off);
            int   oi = __shfl_down(idx, off);
            if (ov > v || (ov == v && oi < idx)) { v = ov; idx = oi; }
        }
        if (tid == 0) sk = idx;
    }
    __syncthreads();
    const int k = sk;
    const int last = (step == NSTEPS - 1);

    // Phase C: node output, new-node state write, final hf/cf
    float* noderow = out + 2 * BH + ((size_t)b * 63 + 32 + step) * NHID;
    if (merge) {
        const int kslot = s_pidx[k];
        const int ns = s_hidx[k];
        for (int h = tid; h < NHID; h += 256) {
            size_t po = ((size_t)kslot * NB + b) * NHID + h;
            float x = pnh[po], cc = pnc[po];
            _Float16 hh = (_Float16)x;
            size_t so = ((size_t)ns * NB + b) * NHID + h;
            hHi[so] = hh;
            hLo[so] = (_Float16)((x - (float)hh) * 2048.f);
            cSt[so] = cc;
            noderow[h] = x;
            if (last) { out[b * NHID + h] = x; out[BH + b * NHID + h] = cc; }
        }
    } else {
        const int s0p = s_pidx[0], s0h = s_hidx[0];
        for (int h = tid; h < NHID; h += 256) {
            if (!last) {
                noderow[h] = pnh[((size_t)s0p * NB + b) * NHID + h];
            } else {
                size_t so = ((size_t)s0h * NB + b) * NHID + h;
                float x = (float)hHi[so] + (float)hLo[so] * INV2048;
                noderow[h] = x;
                out[b * NHID + h] = x;
                out[BH + b * NHID + h] = cSt[so];
            }
        }
    }

    // Phase D: index shifts + next fresh list
    if (tid == 0) {
        if (merge) {
            for (int j2 = k + 1; j2 <= 29; ++j2) pidx[b * 32 + j2] = s_pidx[j2 + 1];
            if (k < 30) pidx[b * 32 + 30] = s_pidx[k + 1];
            for (int p = k + 1; p <= 30; ++p) hidx[b * 32 + p] = s_hidx[p + 1];
            hidx[b * 32 + 31] = HSLOT_Z;
            prevk[b] = k;
            const int nd = (k >= 1) ? 2 : 1;
            int base = atomicAdd(cnt_next, nd);
            if (k >= 1)
                nextlist[base++] = make_int4(b, s_pidx[k - 1], s_hidx[k - 1], s_hidx[k]);
            nextlist[base] = make_int4(b, s_pidx[k], s_hidx[k],
                                       (k + 2 <= 31) ? s_hidx[k + 2] : HSLOT_Z);
        } else {
            prevk[b] = -1;
        }
    }
}

extern "C" void kernel_launch(void* const* d_in, const int* in_sizes, int n_in,
                              void* d_out, int out_size, void* d_ws, size_t ws_size,
                              hipStream_t stream) {
    const float* inp    = (const float*)d_in[0];
    const int*   length = (const int*)d_in[1];
    const float* W_word = (const float*)d_in[2];
    const float* b_word = (const float*)d_in[3];
    const float* W_comp = (const float*)d_in[4];
    const float* b_comp = (const float*)d_in[5];
    const float* q      = (const float*)d_in[6];
    float* out = (float*)d_out;
    float* ws  = (float*)d_ws;

    float*     graw = ws + OFF_GRAW;
    float*     pnh  = ws + OFF_PNH;
    float*     pnc  = ws + OFF_PNC;
    float*     plog = ws + OFF_PLOG;
    float*     cSt  = ws + OFF_CST;
    _Float16*  hHi  = (_Float16*)(ws + OFF_HHI);
    _Float16*  hLo  = (_Float16*)(ws + OFF_HLO);
    _Float16*  Wth  = (_Float16*)(ws + OFF_WTH);
    _Float16*  Wtl  = (_Float16*)(ws + OFF_WTL);
    int*       ireg = (int*)(ws + OFF_INT);
    int*       pidx = ireg;            // 32*32
    int*       hidx = ireg + 1024;     // 32*32
    int*       prevk = ireg + 2048;    // 32
    int*       cnt  = ireg + 2080;     // 2
    int4*      list0 = (int4*)(ws + OFF_LIST);
    int4*      list1 = list0 + 1024;

    init_kernel<<<34, 256, 0, stream>>>(pidx, hidx, prevk, cnt, list0, hHi, hLo, cSt);
    wsplit_kernel<<<dim3(NC5 / 32, 1024 / 32), 256, 0, stream>>>(W_comp, Wth, Wtl);
    word_gemm64<<<dim3(16, 16), 256, 0, stream>>>(inp, W_word, b_word,
                                                  hHi, hLo, cSt, out);
    for (int i = 0; i < NSTEPS; ++i) {
        const int p = i & 1;
        int4* lcur = p ? list1 : list0;
        int4* lnxt = p ? list0 : list1;
        pair_gemm<<<dim3(80, i == 0 ? 31 : 2), 256, 0, stream>>>(
            hHi, hLo, Wth, Wtl, lcur, &cnt[p], &cnt[1 - p], graw);
        update_kernel<<<32, 256, 0, stream>>>(
            graw, b_comp, q, length, pnh, pnc, plog, hHi, hLo, cSt,
            pidx, hidx, prevk, lnxt, &cnt[1 - p], out, i);
    }
}